// Round 4
// baseline (183.344 us; speedup 1.0000x reference)
//
#include <hip/hip_runtime.h>
#include <math.h>

#define EPS_N 1e-12f
#define MARGIN 0.3f
#define INF_BITS 0x7f800000u
#define NCLS 128     // label space (randint(0,128))
#define D 512
#define PADR 256     // padded rows after fh so banded staging can over-read safely

typedef __attribute__((ext_vector_type(8))) short short8;   // 8 bf16 = 4 VGPRs
typedef __attribute__((ext_vector_type(4))) float float4v;  // MFMA 16x16 accum

__device__ __forceinline__ unsigned short f2bf(float f) {   // RNE bf16
    unsigned u = __float_as_uint(f);
    u += 0x7fff + ((u >> 16) & 1);
    return (unsigned short)(u >> 16);
}
__device__ __forceinline__ void gl16(const void* g, void* l) {
    // 16B async global->LDS; global addr per-lane, LDS dest = uniform base + lane*16
    __builtin_amdgcn_global_load_lds((const __attribute__((address_space(1))) void*)g,
                                     (__attribute__((address_space(3))) void*)l, 16, 0, 0);
}

// ---------------------------------------------------------------------------
// K0: one-block bucketing, coalesced-metadata (unchanged).
// ---------------------------------------------------------------------------
__global__ __launch_bounds__(1024) void k_bucket(const int* __restrict__ lab, int Bn,
        int* __restrict__ pos, int* __restrict__ labp,
        int* __restrict__ cstart_g, int* __restrict__ ccnt_g,
        float* __restrict__ meanpos, float* __restrict__ pcinv,
        int* __restrict__ poscnt, unsigned* __restrict__ minbits) {
    __shared__ int cnt[NCLS], cs[NCLS + 1], off[NCLS], sa[NCLS], sb[NCLS];
    int tid = threadIdx.x;
    if (tid < NCLS) cnt[tid] = 0;
    __syncthreads();
    for (int i = tid; i < Bn; i += 1024) atomicAdd(&cnt[lab[i] & (NCLS - 1)], 1);
    __syncthreads();
    if (tid < NCLS) sa[tid] = cnt[tid];
    __syncthreads();
    int* src = sa; int* dst = sb;
    for (int ofs = 1; ofs < NCLS; ofs <<= 1) {          // Hillis-Steele inclusive
        if (tid < NCLS) dst[tid] = src[tid] + ((tid >= ofs) ? src[tid - ofs] : 0);
        __syncthreads();
        int* t = src; src = dst; dst = t;
    }
    if (tid < NCLS) {
        int ex = src[tid] - cnt[tid];                   // exclusive
        cs[tid] = ex;
        off[tid] = ex;
        cstart_g[tid] = ex;
        ccnt_g[tid] = cnt[tid];
    }
    if (tid == 0) cs[NCLS] = Bn;
    __syncthreads();
    // coalesced per-slot metadata: class(p) = largest l with cs[l] <= p
    for (int p = tid; p < Bn; p += 1024) {
        int lo = 0, hi = NCLS - 1;
        #pragma unroll
        for (int s = 0; s < 7; ++s) {
            int mid = (lo + hi + 1) >> 1;
            if (cs[mid] <= p) lo = mid; else hi = mid - 1;
        }
        int l = lo, m = cnt[l];
        labp[p] = l;
        poscnt[p] = m;
        pcinv[p] = 1.0f / (float)m;
        meanpos[p] = 0.f;          // accumulates raw dist-sums (posband3)
        minbits[p] = INF_BITS;
    }
    // pos scatter (reads coalesced; only pos[] store is scattered-by-class)
    for (int i = tid; i < Bn; i += 1024) {
        int l = lab[i] & (NCLS - 1);
        pos[i] = atomicAdd(&off[l], 1);
    }
}

// ---------------------------------------------------------------------------
// K1: normalize; one wave per row, no __syncthreads (unchanged).
// ---------------------------------------------------------------------------
__global__ __launch_bounds__(256) void k_normalize(const float* __restrict__ x,
        const int* __restrict__ pos, unsigned short* __restrict__ fh,
        float* __restrict__ sqp) {
    int w = threadIdx.x >> 6, L = threadIdx.x & 63;
    int row = blockIdx.x * 4 + w;
    const float* xr = x + (size_t)row * D + L * 8;
    float4 a = *(const float4*)xr;
    float4 b = *(const float4*)(xr + 4);
    float ss = a.x * a.x;
    ss = fmaf(a.y, a.y, ss); ss = fmaf(a.z, a.z, ss); ss = fmaf(a.w, a.w, ss);
    ss = fmaf(b.x, b.x, ss); ss = fmaf(b.y, b.y, ss);
    ss = fmaf(b.z, b.z, ss); ss = fmaf(b.w, b.w, ss);
    #pragma unroll
    for (int off = 32; off; off >>= 1) ss += __shfl_xor(ss, off, 64);
    float inv = 1.0f / fmaxf(sqrtf(ss), EPS_N);
    int prow = pos[row];
    if (L == 0) sqp[prow] = ss * inv * inv;
    ushort4 h0, h1;
    h0.x = f2bf(a.x * inv); h0.y = f2bf(a.y * inv);
    h0.z = f2bf(a.z * inv); h0.w = f2bf(a.w * inv);
    h1.x = f2bf(b.x * inv); h1.y = f2bf(b.y * inv);
    h1.z = f2bf(b.z * inv); h1.w = f2bf(b.w * inv);
    unsigned short* dst = fh + (size_t)prow * D + L * 8;
    *(ushort4*)dst = h0;
    *(ushort4*)(dst + 4) = h1;
}

// ---------------------------------------------------------------------------
// K2: banded positive stats v3 (unchanged).
// ---------------------------------------------------------------------------
__global__ __launch_bounds__(256) void k_posband3(
    const unsigned short* __restrict__ fh, const float* __restrict__ sqp,
    const int* __restrict__ labp, const int* __restrict__ cstart_g,
    const int* __restrict__ ccnt_g, float* __restrict__ meanpos, int Bn)
{
    __shared__ unsigned short SA[16 * 128];    // 4 KB per K-chunk
    __shared__ unsigned short SB[128 * 128];   // 32 KB per K-chunk
    __shared__ float sqr[16], rs[16];
    __shared__ int labr[16];
    __shared__ float sqc[128];
    __shared__ int labc[128];

    const int r0 = blockIdx.x * 16;
    const int tid = threadIdx.x, w = tid >> 6, L = tid & 63;
    const int lm = L & 15, ls = L >> 4;
    const int srow = L >> 4;      // 0..3 rows per gl16 group
    const int sseg = L & 15;      // 16-B seg slot within a 256 B row

    if (tid < 16) {
        labr[tid] = labp[r0 + tid];
        sqr[tid]  = sqp[r0 + tid];
        rs[tid]   = 0.f;
    }
    __syncthreads();
    const int c0 = cstart_g[labr[0]];
    const int c1 = cstart_g[labr[15]] + ccnt_g[labr[15]];

    for (int cc0 = c0; cc0 < c1; cc0 += 128) {
        __syncthreads();
        if (tid < 128) {
            int q = cc0 + tid;
            if (q < Bn) { sqc[tid] = sqp[q]; labc[tid] = labp[q]; }
            else        { sqc[tid] = 0.f;    labc[tid] = -1; }
        }
        float4v acc[2];
        acc[0] = (float4v){0.f, 0.f, 0.f, 0.f};
        acc[1] = (float4v){0.f, 0.f, 0.f, 0.f};

        for (int k0 = 0; k0 < D; k0 += 128) {
            __syncthreads();
            {   // SA: wave w stages rows w*4 .. w*4+3 (one gl16)
                int rmat = w * 4 + srow;
                int seg = sseg ^ (rmat & 15);
                gl16(fh + (size_t)(r0 + rmat) * D + k0 + seg * 8, &SA[(w * 4) * 128]);
            }
            #pragma unroll
            for (int it = 0; it < 8; ++it) {  // SB: 32 gl16 across 4 waves
                int rmat = it * 16 + w * 4 + srow;          // 0..127 (may over-read pad)
                int seg = sseg ^ (rmat & 15);
                gl16(fh + (size_t)(cc0 + rmat) * D + k0 + seg * 8,
                     &SB[(size_t)(it * 16 + w * 4) * 128]);
            }
            __syncthreads();
            #pragma unroll
            for (int h = 0; h < 4; ++h) {      // K=128 in 4 MFMA sub-steps
                int ra = lm;
                short8 af = *(const short8*)&SA[ra * 128 + (((h * 4 + ls) ^ (ra & 15))) * 8];
                #pragma unroll
                for (int ct = 0; ct < 2; ++ct) {
                    int rb = w * 32 + ct * 16 + lm;
                    short8 bf = *(const short8*)&SB[rb * 128 + (((h * 4 + ls) ^ (rb & 15))) * 8];
                    acc[ct] = __builtin_amdgcn_mfma_f32_16x16x32_bf16(af, bf, acc[ct], 0, 0, 0);
                }
            }
        }
        // epilogue: masked dist row-sums. C/D: row = ls*4+v, col = w*32+ct*16+lm
        #pragma unroll
        for (int v = 0; v < 4; ++v) {
            int ri = ls * 4 + v;
            int p = r0 + ri;
            int lr = labr[ri];
            float sr = sqr[ri];
            float sum = 0.f;
            #pragma unroll
            for (int ct = 0; ct < 2; ++ct) {
                int ci = w * 32 + ct * 16 + lm;
                int q = cc0 + ci;
                float d2 = sr + sqc[ci] - 2.0f * acc[ct][v];
                float dd = (d2 > 0.f) ? sqrtf(d2) : 0.f;
                sum += ((labc[ci] == lr) && (q != p)) ? dd : 0.f;
            }
            #pragma unroll
            for (int off = 8; off; off >>= 1) sum += __shfl_xor(sum, off, 64);
            if (lm == 0) atomicAdd(&rs[ri], sum);
        }
    }
    __syncthreads();
    if (tid < 16 && rs[tid] != 0.f) atomicAdd(&meanpos[r0 + tid], rs[tid]);
}

// ---------------------------------------------------------------------------
// K3 (R15): faithful m201-style 8-phase port. 256x256 tile, 8 waves (2Mx4N,
// wave=128x64, acc 8x4), BK=64, tile-level dbuf (tile t -> buf[t&1]).
// Per K-tile: 4 phases, EACH = { ds_read subtile; stage 1 half-tile;
//   s_barrier; lgkmcnt(0)+sched_barrier; setprio(1) 16 MFMA setprio(0);
//   s_barrier }  -- per-phase lockstep (m201/m196: this is the lever).
// Stagger: tile t stages hf1,hf2,hf3(t+1) at p0-p2 (free buffer) and
// hf0(t+2) at p3 post-lgkm (timing-safe: gl16 latency >> ds_read latency).
// vmcnt(2) once per tile before the closing barrier: at that point
// outstanding = hf0..3(t+1)[8] + hf0(t+2)[2] -> drains tile t+1 fully,
// leaves hf0(t+2) in flight. Never vmcnt(0) until the pipeline tail.
// Grid: 528 triangular blocks (=8*66, bijective XCD swizzle), 1 block/CU.
// ---------------------------------------------------------------------------
#define NKT 8           // K-tiles of BK=64 over D=512
#define BUFH 32768      // ushorts per buffer: A 16384 | B 16384 (64 KB)

__global__ __launch_bounds__(512, 2) void k_minsh_mfma(
    const unsigned short* __restrict__ fh, const float* __restrict__ sqp,
    const int* __restrict__ labp, const float* __restrict__ meanpos,
    const float* __restrict__ pcinv, unsigned* __restrict__ minbits)
{
    // --- XCD swizzle (528 = 8*66, bijective) + triangular decode ---
    int t = (blockIdx.x & 7) * 66 + (blockIdx.x >> 3);
    int I = (int)((sqrtf(8.0f * (float)t + 1.0f) - 1.0f) * 0.5f);
    while ((I + 1) * (I + 2) / 2 <= t) ++I;
    while (I * (I + 1) / 2 > t) --I;
    const int J = t - I * (I + 1) / 2;
    const int i0 = I * 256, j0 = J * 256;

    __shared__ unsigned short LA[2 * BUFH];                // 128 KB flat
    __shared__ float s_mp2r[256], s_sqr[256], s_mp2c[256], s_sqc[256];
    __shared__ int s_labr[256], s_labc[256];

    const int tid = threadIdx.x;
    const int w = tid >> 6, L = tid & 63;
    const int lm = L & 15, ls = L >> 4;
    const int wm = w >> 2, wn = w & 3;          // 2M x 4N wave grid
    const int u0 = ls ^ (lm & 7);               // k-step 0 swizzled segment
    const int u1 = u0 ^ 4;                      // k-step 1 ((4|ls)^swz, ls<4)

    // --- pre-swizzled staging sources: LDS[r][e] holds global seg e^(r&7) ---
    const unsigned short* srcA[4];
    const unsigned short* srcB[4];
    #pragma unroll
    for (int q = 0; q < 4; ++q) {
        int s = tid + 512 * q;                  // 16B slot 0..2047
        int r = s >> 3;                         // row 0..255
        int u = (s & 7) ^ (r & 7);              // global segment for this slot
        srcA[q] = fh + (size_t)(i0 + r) * D + u * 8;
        srcB[q] = fh + (size_t)(j0 + r) * D + u * 8;
    }
    unsigned short* LAm = &LA[0];
    const unsigned short* aB = LAm + (wm * 128 + lm) * 64;
    const unsigned short* bB = LAm + 16384 + (wn * 64 + lm) * 64;

    // half-tile stage: hf 0/1 = A rows 0-127/128-255, hf 2/3 = B (2x gl16)
#define STAGE_HF(t_, hf_) do {                                               \
    int ko_ = (t_) * 64;                                                     \
    unsigned short* db_ = LAm + ((t_) & 1) * BUFH + (((hf_) >= 2) ? 16384 : 0); \
    const unsigned short* const* sp_ = ((hf_) >= 2) ? srcB : srcA;           \
    int q0_ = ((hf_) & 1) * 2;                                               \
    gl16(sp_[q0_] + ko_,     db_ + (w * 64 + 512 * q0_) * 8);                \
    gl16(sp_[q0_ + 1] + ko_, db_ + (w * 64 + 512 * (q0_ + 1)) * 8);          \
} while (0)

#define MM16(mlo_)                                                           \
    __builtin_amdgcn_s_setprio(1);                                           \
    _Pragma("unroll")                                                        \
    for (int ni = 0; ni < 4; ++ni) {                                         \
        _Pragma("unroll")                                                    \
        for (int k = 0; k < 4; ++k)                                          \
            acc[(mlo_) + k][ni] = __builtin_amdgcn_mfma_f32_16x16x32_bf16(   \
                af[k], bf[ni], acc[(mlo_) + k][ni], 0, 0, 0);                 \
    }                                                                        \
    __builtin_amdgcn_s_setprio(0);

#define SB0()   __builtin_amdgcn_sched_barrier(0)
#define BAR()   do { SB0(); __builtin_amdgcn_s_barrier(); SB0(); } while (0)
#define LGKM0() do { asm volatile("s_waitcnt lgkmcnt(0)" ::: "memory"); SB0(); } while (0)

    // GROUP: one K-tile, 4 lockstep phases. DO1 = stage hf1-3(t+1);
    // DO0 = stage hf0(t+2); WAITK = 2 steady / 0 at g=NKT-2 / -1 last.
#define GROUP(co_, g_, DO1_, DO0_, WAITK_) do {                              \
    short8 af[4], bf[4];                                                     \
    /* ---- p0: B(u0)+A03(u0) | hf1(t+1) | MFMA acc[0..3] ---- */            \
    _Pragma("unroll")                                                        \
    for (int ni = 0; ni < 4; ++ni) bf[ni] = *(const short8*)(bB + (co_) + ni * 1024 + u0 * 8); \
    _Pragma("unroll")                                                        \
    for (int k = 0; k < 4; ++k)  af[k] = *(const short8*)(aB + (co_) + k * 1024 + u0 * 8); \
    if (DO1_) STAGE_HF((g_) + 1, 1);                                         \
    BAR(); LGKM0();                                                          \
    MM16(0);                                                                 \
    BAR();                                                                   \
    /* ---- p1: A47(u0) | hf2(t+1) | MFMA acc[4..7] ---- */                  \
    _Pragma("unroll")                                                        \
    for (int k = 0; k < 4; ++k)  af[k] = *(const short8*)(aB + (co_) + (4 + k) * 1024 + u0 * 8); \
    if (DO1_) STAGE_HF((g_) + 1, 2);                                         \
    BAR(); LGKM0();                                                          \
    MM16(4);                                                                 \
    BAR();                                                                   \
    /* ---- p2: B(u1)+A03(u1) | hf3(t+1) | MFMA acc[0..3] ---- */            \
    _Pragma("unroll")                                                        \
    for (int ni = 0; ni < 4; ++ni) bf[ni] = *(const short8*)(bB + (co_) + ni * 1024 + u1 * 8); \
    _Pragma("unroll")                                                        \
    for (int k = 0; k < 4; ++k)  af[k] = *(const short8*)(aB + (co_) + k * 1024 + u1 * 8); \
    if (DO1_) STAGE_HF((g_) + 1, 3);                                         \
    BAR(); LGKM0();                                                          \
    MM16(0);                                                                 \
    BAR();                                                                   \
    /* ---- p3: A47(u1) | hf0(t+2) post-lgkm | MFMA acc[4..7] | vmcnt ---- */ \
    _Pragma("unroll")                                                        \
    for (int k = 0; k < 4; ++k)  af[k] = *(const short8*)(aB + (co_) + (4 + k) * 1024 + u1 * 8); \
    BAR(); LGKM0();                                                          \
    if (DO0_) STAGE_HF((g_) + 2, 0);                                         \
    MM16(4);                                                                 \
    if ((WAITK_) == 2)      { asm volatile("s_waitcnt vmcnt(2)" ::: "memory"); } \
    else if ((WAITK_) == 0) { asm volatile("s_waitcnt vmcnt(0)" ::: "memory"); } \
    SB0();                                                                   \
    if ((WAITK_) >= 0) { __builtin_amdgcn_s_barrier(); SB0(); }              \
} while (0)

    // --- metadata first (loads consumed before stages; pinned by sched_barrier)
    if (tid < 256) {
        int p = i0 + tid;
        float mp = meanpos[p] * pcinv[p];
        s_mp2r[tid] = mp * mp;
        s_sqr[tid]  = sqp[p];
        s_labr[tid] = labp[p];
    } else {
        int q = tid - 256, p = j0 + q;
        float mp = meanpos[p] * pcinv[p];
        s_mp2c[q] = mp * mp;
        s_sqc[q]  = sqp[p];
        s_labc[q] = labp[p];
    }
    SB0();

    float4v acc[8][4];
    #pragma unroll
    for (int mi = 0; mi < 8; ++mi)
        #pragma unroll
        for (int ni = 0; ni < 4; ++ni) acc[mi][ni] = (float4v){0.f, 0.f, 0.f, 0.f};

    // --- prologue: t0 full (8 loads) + hf0(t1) (2); wait t0 only ---
    STAGE_HF(0, 0); STAGE_HF(0, 1); STAGE_HF(0, 2); STAGE_HF(0, 3);
    STAGE_HF(1, 0);
    asm volatile("s_waitcnt vmcnt(2)" ::: "memory");   // t0 landed; hf0(t1) in flight
    BAR();

    // --- 8 K-tiles: 0..5 uniform; 6,7 peeled ---
    #pragma unroll
    for (int g = 0; g < NKT - 2; ++g) {
        const int co = (g & 1) * BUFH;
        GROUP(co, g, true, true, 2);
    }
    GROUP(((NKT - 2) & 1) * BUFH, NKT - 2, true,  false, 0);   // g=6: drain t7
    GROUP(((NKT - 1) & 1) * BUFH, NKT - 1, false, false, -1);  // g=7: compute only

#undef GROUP
#undef LGKM0
#undef BAR
#undef SB0
#undef MM16
#undef STAGE_HF

    // --- epilogue: dual-side semi-hard mins, LDS-combined ---
    // C/D: row = wm*128 + mi*16 + ls*4 + v, col = wn*64 + ni*16 + lm
    unsigned* rminb = (unsigned*)&LA[0];        // LA dead; reuse
    unsigned* cminb = rminb + 256;
    __syncthreads();
    if (tid < 256) rminb[tid] = INF_BITS;
    else           cminb[tid - 256] = INF_BITS;
    __syncthreads();

    const float INFF = __uint_as_float(INF_BITS);
    float sc[4], mp2c[4]; int lc[4];
    #pragma unroll
    for (int ni = 0; ni < 4; ++ni) {
        int cl = wn * 64 + ni * 16 + lm;
        sc[ni]   = s_sqc[cl];
        mp2c[ni] = s_mp2c[cl];
        lc[ni]   = s_labc[cl];
    }
    float vminc[4];
    #pragma unroll
    for (int ni = 0; ni < 4; ++ni) vminc[ni] = INFF;

    #pragma unroll
    for (int mi = 0; mi < 8; ++mi) {
        #pragma unroll
        for (int v = 0; v < 4; ++v) {
            int rl = wm * 128 + mi * 16 + ls * 4 + v;
            float mp2r = s_mp2r[rl];
            float sr   = s_sqr[rl];
            int   li   = s_labr[rl];
            float vminr = INFF;
            #pragma unroll
            for (int ni = 0; ni < 4; ++ni) {
                float d2 = fmaf(-2.0f, acc[mi][ni][v], sr + sc[ni]);
                bool neq = (li != lc[ni]);
                vminr     = fminf(vminr,     (neq && d2 > mp2r)     ? d2 : INFF);
                vminc[ni] = fminf(vminc[ni], (neq && d2 > mp2c[ni]) ? d2 : INFF);
            }
            #pragma unroll
            for (int off = 8; off; off >>= 1)
                vminr = fminf(vminr, __shfl_xor(vminr, off, 64));
            if (lm == 0 && __float_as_uint(vminr) != INF_BITS)
                atomicMin(&rminb[rl], __float_as_uint(vminr));
        }
    }
    #pragma unroll
    for (int ni = 0; ni < 4; ++ni) {
        float vc = vminc[ni];
        vc = fminf(vc, __shfl_xor(vc, 16, 64));
        vc = fminf(vc, __shfl_xor(vc, 32, 64));
        if (ls == 0 && __float_as_uint(vc) != INF_BITS)
            atomicMin(&cminb[wn * 64 + ni * 16 + lm], __float_as_uint(vc));
    }
    __syncthreads();
    if (tid < 256) {
        unsigned rb = rminb[tid];
        if (rb != INF_BITS) atomicMin(&minbits[i0 + tid], rb);
    } else if (i0 != j0) {
        unsigned cb = cminb[tid - 256];
        if (cb != INF_BITS) atomicMin(&minbits[j0 + tid - 256], cb);
    }
}

// ---------------------------------------------------------------------------
// K4: final reduction (unchanged).
// ---------------------------------------------------------------------------
__global__ __launch_bounds__(1024) void k_finish(const float* __restrict__ meanpos,
        const float* __restrict__ pcinv, const int* __restrict__ poscnt,
        const unsigned* __restrict__ minbits, float* __restrict__ out, int Bn) {
    float lsum = 0.f; int lcnt = 0;
    for (int i = threadIdx.x; i < Bn; i += 1024) {
        int pc = poscnt[i];
        bool valid = (pc > 1) && (pc < Bn);
        unsigned mb = minbits[i];
        if (valid && mb != INF_BITS) {
            float v = fmaf(meanpos[i], pcinv[i], MARGIN - sqrtf(__uint_as_float(mb)));
            lsum += (v > 0.f) ? v : 0.f;
            lcnt += 1;
        }
    }
    __shared__ float ssum[16]; __shared__ int scnt[16];
    int lane = threadIdx.x & 63, wid = threadIdx.x >> 6;
    #pragma unroll
    for (int off = 32; off; off >>= 1) {
        lsum += __shfl_down(lsum, off, 64);
        lcnt += __shfl_down(lcnt, off, 64);
    }
    if (lane == 0) { ssum[wid] = lsum; scnt[wid] = lcnt; }
    __syncthreads();
    if (threadIdx.x == 0) {
        float s = 0.f; int c = 0;
        #pragma unroll
        for (int q = 0; q < 16; ++q) { s += ssum[q]; c += scnt[q]; }
        out[0] = (c > 0) ? s / (float)c : 0.f;
    }
}

// ---------------------------------------------------------------------------
extern "C" void kernel_launch(void* const* d_in, const int* in_sizes, int n_in,
                              void* d_out, int out_size, void* d_ws, size_t ws_size,
                              hipStream_t stream) {
    const float* x = (const float*)d_in[0];
    const int* lab = (const int*)d_in[1];
    int Bn = in_sizes[1];                 // 8192; D fixed at 512

    size_t nd = (size_t)(Bn + PADR) * D;  // padded for banded over-read (K2)
    unsigned short* fh = (unsigned short*)d_ws;
    float* sqp        = (float*)(fh + nd);
    float* meanpos    = sqp + Bn;         // raw dist-sums
    float* pcinv      = meanpos + Bn;
    int* poscnt       = (int*)(pcinv + Bn);
    unsigned* minbits = (unsigned*)(poscnt + Bn);
    int* pos          = (int*)(minbits + Bn);
    int* labp         = pos + Bn;
    int* cstart_g     = labp + Bn;
    int* ccnt_g       = cstart_g + NCLS;

    k_bucket<<<1, 1024, 0, stream>>>(lab, Bn, pos, labp, cstart_g, ccnt_g,
                                     meanpos, pcinv, poscnt, minbits);
    k_normalize<<<Bn / 4, 256, 0, stream>>>(x, pos, fh, sqp);
    k_posband3<<<Bn / 16, 256, 0, stream>>>(fh, sqp, labp, cstart_g, ccnt_g,
                                            meanpos, Bn);
    int nbr = Bn / 256;                   // 32 row-tiles
    int T = nbr * (nbr + 1) / 2;          // 528 triangular 256x256 tiles
    k_minsh_mfma<<<T, 512, 0, stream>>>(fh, sqp, labp, meanpos, pcinv, minbits);
    k_finish<<<1, 1024, 0, stream>>>(meanpos, pcinv, poscnt, minbits,
                                     (float*)d_out, Bn);
}

// Round 5
// 177.814 us; speedup vs baseline: 1.0311x; 1.0311x over previous
//
#include <hip/hip_runtime.h>
#include <math.h>

#define EPS_N 1e-12f
#define MARGIN 0.3f
#define INF_BITS 0x7f800000u
#define NCLS 128     // label space (randint(0,128))
#define D 512
#define PADR 256     // padded rows after fh so banded staging can over-read safely

typedef __attribute__((ext_vector_type(8))) short short8;   // 8 bf16 = 4 VGPRs
typedef __attribute__((ext_vector_type(4))) float float4v;  // MFMA 16x16 accum

__device__ __forceinline__ unsigned short f2bf(float f) {   // RNE bf16
    unsigned u = __float_as_uint(f);
    u += 0x7fff + ((u >> 16) & 1);
    return (unsigned short)(u >> 16);
}
__device__ __forceinline__ void gl16(const void* g, void* l) {
    // 16B async global->LDS; global addr per-lane, LDS dest = uniform base + lane*16
    __builtin_amdgcn_global_load_lds((const __attribute__((address_space(1))) void*)g,
                                     (__attribute__((address_space(3))) void*)l, 16, 0, 0);
}

// ---------------------------------------------------------------------------
// K0: one-block bucketing, coalesced-metadata (unchanged).
// ---------------------------------------------------------------------------
__global__ __launch_bounds__(1024) void k_bucket(const int* __restrict__ lab, int Bn,
        int* __restrict__ pos, int* __restrict__ labp,
        int* __restrict__ cstart_g, int* __restrict__ ccnt_g,
        float* __restrict__ meanpos, float* __restrict__ pcinv,
        int* __restrict__ poscnt, unsigned* __restrict__ minbits) {
    __shared__ int cnt[NCLS], cs[NCLS + 1], off[NCLS], sa[NCLS], sb[NCLS];
    int tid = threadIdx.x;
    if (tid < NCLS) cnt[tid] = 0;
    __syncthreads();
    for (int i = tid; i < Bn; i += 1024) atomicAdd(&cnt[lab[i] & (NCLS - 1)], 1);
    __syncthreads();
    if (tid < NCLS) sa[tid] = cnt[tid];
    __syncthreads();
    int* src = sa; int* dst = sb;
    for (int ofs = 1; ofs < NCLS; ofs <<= 1) {          // Hillis-Steele inclusive
        if (tid < NCLS) dst[tid] = src[tid] + ((tid >= ofs) ? src[tid - ofs] : 0);
        __syncthreads();
        int* t = src; src = dst; dst = t;
    }
    if (tid < NCLS) {
        int ex = src[tid] - cnt[tid];                   // exclusive
        cs[tid] = ex;
        off[tid] = ex;
        cstart_g[tid] = ex;
        ccnt_g[tid] = cnt[tid];
    }
    if (tid == 0) cs[NCLS] = Bn;
    __syncthreads();
    // coalesced per-slot metadata: class(p) = largest l with cs[l] <= p
    for (int p = tid; p < Bn; p += 1024) {
        int lo = 0, hi = NCLS - 1;
        #pragma unroll
        for (int s = 0; s < 7; ++s) {
            int mid = (lo + hi + 1) >> 1;
            if (cs[mid] <= p) lo = mid; else hi = mid - 1;
        }
        int l = lo, m = cnt[l];
        labp[p] = l;
        poscnt[p] = m;
        pcinv[p] = 1.0f / (float)m;
        meanpos[p] = 0.f;          // accumulates raw dist-sums (posband3)
        minbits[p] = INF_BITS;
    }
    // pos scatter (reads coalesced; only pos[] store is scattered-by-class)
    for (int i = tid; i < Bn; i += 1024) {
        int l = lab[i] & (NCLS - 1);
        pos[i] = atomicAdd(&off[l], 1);
    }
}

// ---------------------------------------------------------------------------
// K1: normalize; one wave per row, no __syncthreads (unchanged).
// ---------------------------------------------------------------------------
__global__ __launch_bounds__(256) void k_normalize(const float* __restrict__ x,
        const int* __restrict__ pos, unsigned short* __restrict__ fh,
        float* __restrict__ sqp) {
    int w = threadIdx.x >> 6, L = threadIdx.x & 63;
    int row = blockIdx.x * 4 + w;
    const float* xr = x + (size_t)row * D + L * 8;
    float4 a = *(const float4*)xr;
    float4 b = *(const float4*)(xr + 4);
    float ss = a.x * a.x;
    ss = fmaf(a.y, a.y, ss); ss = fmaf(a.z, a.z, ss); ss = fmaf(a.w, a.w, ss);
    ss = fmaf(b.x, b.x, ss); ss = fmaf(b.y, b.y, ss);
    ss = fmaf(b.z, b.z, ss); ss = fmaf(b.w, b.w, ss);
    #pragma unroll
    for (int off = 32; off; off >>= 1) ss += __shfl_xor(ss, off, 64);
    float inv = 1.0f / fmaxf(sqrtf(ss), EPS_N);
    int prow = pos[row];
    if (L == 0) sqp[prow] = ss * inv * inv;
    ushort4 h0, h1;
    h0.x = f2bf(a.x * inv); h0.y = f2bf(a.y * inv);
    h0.z = f2bf(a.z * inv); h0.w = f2bf(a.w * inv);
    h1.x = f2bf(b.x * inv); h1.y = f2bf(b.y * inv);
    h1.z = f2bf(b.z * inv); h1.w = f2bf(b.w * inv);
    unsigned short* dst = fh + (size_t)prow * D + L * 8;
    *(ushort4*)dst = h0;
    *(ushort4*)(dst + 4) = h1;
}

// ---------------------------------------------------------------------------
// K2: banded positive stats v3 (unchanged).
// ---------------------------------------------------------------------------
__global__ __launch_bounds__(256) void k_posband3(
    const unsigned short* __restrict__ fh, const float* __restrict__ sqp,
    const int* __restrict__ labp, const int* __restrict__ cstart_g,
    const int* __restrict__ ccnt_g, float* __restrict__ meanpos, int Bn)
{
    __shared__ unsigned short SA[16 * 128];    // 4 KB per K-chunk
    __shared__ unsigned short SB[128 * 128];   // 32 KB per K-chunk
    __shared__ float sqr[16], rs[16];
    __shared__ int labr[16];
    __shared__ float sqc[128];
    __shared__ int labc[128];

    const int r0 = blockIdx.x * 16;
    const int tid = threadIdx.x, w = tid >> 6, L = tid & 63;
    const int lm = L & 15, ls = L >> 4;
    const int srow = L >> 4;      // 0..3 rows per gl16 group
    const int sseg = L & 15;      // 16-B seg slot within a 256 B row

    if (tid < 16) {
        labr[tid] = labp[r0 + tid];
        sqr[tid]  = sqp[r0 + tid];
        rs[tid]   = 0.f;
    }
    __syncthreads();
    const int c0 = cstart_g[labr[0]];
    const int c1 = cstart_g[labr[15]] + ccnt_g[labr[15]];

    for (int cc0 = c0; cc0 < c1; cc0 += 128) {
        __syncthreads();
        if (tid < 128) {
            int q = cc0 + tid;
            if (q < Bn) { sqc[tid] = sqp[q]; labc[tid] = labp[q]; }
            else        { sqc[tid] = 0.f;    labc[tid] = -1; }
        }
        float4v acc[2];
        acc[0] = (float4v){0.f, 0.f, 0.f, 0.f};
        acc[1] = (float4v){0.f, 0.f, 0.f, 0.f};

        for (int k0 = 0; k0 < D; k0 += 128) {
            __syncthreads();
            {   // SA: wave w stages rows w*4 .. w*4+3 (one gl16)
                int rmat = w * 4 + srow;
                int seg = sseg ^ (rmat & 15);
                gl16(fh + (size_t)(r0 + rmat) * D + k0 + seg * 8, &SA[(w * 4) * 128]);
            }
            #pragma unroll
            for (int it = 0; it < 8; ++it) {  // SB: 32 gl16 across 4 waves
                int rmat = it * 16 + w * 4 + srow;          // 0..127 (may over-read pad)
                int seg = sseg ^ (rmat & 15);
                gl16(fh + (size_t)(cc0 + rmat) * D + k0 + seg * 8,
                     &SB[(size_t)(it * 16 + w * 4) * 128]);
            }
            __syncthreads();
            #pragma unroll
            for (int h = 0; h < 4; ++h) {      // K=128 in 4 MFMA sub-steps
                int ra = lm;
                short8 af = *(const short8*)&SA[ra * 128 + (((h * 4 + ls) ^ (ra & 15))) * 8];
                #pragma unroll
                for (int ct = 0; ct < 2; ++ct) {
                    int rb = w * 32 + ct * 16 + lm;
                    short8 bf = *(const short8*)&SB[rb * 128 + (((h * 4 + ls) ^ (rb & 15))) * 8];
                    acc[ct] = __builtin_amdgcn_mfma_f32_16x16x32_bf16(af, bf, acc[ct], 0, 0, 0);
                }
            }
        }
        // epilogue: masked dist row-sums. C/D: row = ls*4+v, col = w*32+ct*16+lm
        #pragma unroll
        for (int v = 0; v < 4; ++v) {
            int ri = ls * 4 + v;
            int p = r0 + ri;
            int lr = labr[ri];
            float sr = sqr[ri];
            float sum = 0.f;
            #pragma unroll
            for (int ct = 0; ct < 2; ++ct) {
                int ci = w * 32 + ct * 16 + lm;
                int q = cc0 + ci;
                float d2 = sr + sqc[ci] - 2.0f * acc[ct][v];
                float dd = (d2 > 0.f) ? sqrtf(d2) : 0.f;
                sum += ((labc[ci] == lr) && (q != p)) ? dd : 0.f;
            }
            #pragma unroll
            for (int off = 8; off; off >>= 1) sum += __shfl_xor(sum, off, 64);
            if (lm == 0) atomicAdd(&rs[ri], sum);
        }
    }
    __syncthreads();
    if (tid < 16 && rs[tid] != 0.f) atomicAdd(&meanpos[r0 + tid], rs[tid]);
}

// ---------------------------------------------------------------------------
// K3 (R16): back to the PROVEN R8 2-barrier structure (which measured at
// ~97% of its LDS-BW ceiling), with geometry chosen to cut LDS bytes/FLOP:
// 256x128 tile, 4 waves (2Mx2N), wave = 128x64, acc 8x4. Per K=32 slice:
// reads 4x(8+4)x1KB = 48 KB + gl16 writes 24 KB = 576 LDS-cy vs 155 MFMA-cy
// -> 27% MfmaUtil ceiling (R8 was 20%). VGPR ~230 -> 2 blocks/CU keeps the
// cross-block antiphase that let R8 reach its ceiling. Grid: 1056 triangular
// 256x128 blocks (row-tile I has 2I+2 col-tiles; every unordered pair
// covered via dual-side idempotent atomicMin), 1056 = 8*132 XCD-bijective.
// ---------------------------------------------------------------------------
#define BKG 64
#define NK8 8           // D / BKG

__global__ __launch_bounds__(256, 2) void k_minsh_mfma(
    const unsigned short* __restrict__ fh, const float* __restrict__ sqp,
    const int* __restrict__ labp, const float* __restrict__ meanpos,
    const float* __restrict__ pcinv, unsigned* __restrict__ minbits)
{
    // --- XCD swizzle (1056 = 8*132, bijective) + triangular-band decode ---
    int t = (blockIdx.x & 7) * 132 + (blockIdx.x >> 3);
    // blocks before row-tile I: C(I) = I*(I+1); row I has 2I+2 col-tiles
    int I = (int)((sqrtf(4.0f * (float)t + 1.0f) - 1.0f) * 0.5f);
    while ((I + 1) * (I + 2) <= t) ++I;
    while (I * (I + 1) > t) --I;
    const int J = t - I * (I + 1);
    const int i0 = I * 256;      // 256 output rows
    const int j0 = J * 128;      // 128 output cols (j0 <= i0+128)

    __shared__ unsigned short SA[256 * BKG];   // 32 KB
    __shared__ unsigned short SB[128 * BKG];   // 16 KB
    __shared__ float s_mp2r[256], s_sqr[256], s_mp2c[128], s_sqc[128];
    __shared__ int s_labr[256], s_labc[128];

    const int tid = threadIdx.x;
    const int w = tid >> 6, L = tid & 63;
    const int lm = L & 15, ls = L >> 4;
    const int wm = w >> 1, wn = w & 1;          // 2M x 2N wave grid

    // metadata (each thread fills its own slots; barrier below covers it)
    {
        int p = i0 + tid;
        float mp = meanpos[p] * pcinv[p];
        s_mp2r[tid] = mp * mp;
        s_sqr[tid]  = sqp[p];
        s_labr[tid] = labp[p];
        if (tid < 128) {
            int pq = j0 + tid;
            float mq = meanpos[pq] * pcinv[pq];
            s_mp2c[tid] = mq * mq;
            s_sqc[tid]  = sqp[pq];
            s_labc[tid] = labp[pq];
        }
    }

    // --- pre-swizzled staging sources (both-sides XOR swizzle, R8-proven):
    // LDS slot s = (row r, seg e) holds global seg u = e ^ (r&7).
    const unsigned short* srcA[8];
    #pragma unroll
    for (int q = 0; q < 8; ++q) {
        int s = tid + 256 * q;                  // A slot 0..2047
        int r = s >> 3;
        int u = (s & 7) ^ (r & 7);
        srcA[q] = fh + (size_t)(i0 + r) * D + u * 8;
    }
    const unsigned short* srcB[4];
    #pragma unroll
    for (int q = 0; q < 4; ++q) {
        int s = tid + 256 * q;                  // B slot 0..1023
        int r = s >> 3;
        int u = (s & 7) ^ (r & 7);
        srcB[q] = fh + (size_t)(j0 + r) * D + u * 8;
    }

    float4v acc[8][4];
    #pragma unroll
    for (int mi = 0; mi < 8; ++mi)
        #pragma unroll
        for (int ni = 0; ni < 4; ++ni) acc[mi][ni] = (float4v){0.f, 0.f, 0.f, 0.f};

    for (int kt = 0; kt < NK8; ++kt) {
        const int ko = kt * BKG;                // ushort offset of K-chunk
        __syncthreads();                        // prev compute done; buf free
        #pragma unroll
        for (int q = 0; q < 8; ++q)
            gl16(srcA[q] + ko, &SA[(w * 64 + 256 * q) * 8]);
        #pragma unroll
        for (int q = 0; q < 4; ++q)
            gl16(srcB[q] + ko, &SB[(w * 64 + 256 * q) * 8]);
        __syncthreads();                        // drains vmcnt: tile landed
        #pragma unroll
        for (int h = 0; h < 2; ++h) {
            short8 af[8], bf[4];
            #pragma unroll
            for (int mi = 0; mi < 8; ++mi) {
                int r = wm * 128 + mi * 16 + lm;
                af[mi] = *(const short8*)&SA[r * 64 + ((h * 4 + ls) ^ (r & 7)) * 8];
            }
            #pragma unroll
            for (int ni = 0; ni < 4; ++ni) {
                int rb = wn * 64 + ni * 16 + lm;
                bf[ni] = *(const short8*)&SB[rb * 64 + ((h * 4 + ls) ^ (rb & 7)) * 8];
            }
            #pragma unroll
            for (int ni = 0; ni < 4; ++ni)
                #pragma unroll
                for (int mi = 0; mi < 8; ++mi)
                    acc[mi][ni] = __builtin_amdgcn_mfma_f32_16x16x32_bf16(af[mi], bf[ni], acc[mi][ni], 0, 0, 0);
        }
    }

    // --- d2-space dual-side epilogue (R12-verified math).
    // C/D: row = wm*128 + mi*16 + ls*4 + v, col = wn*64 + ni*16 + lm
    const float INFF = __uint_as_float(INF_BITS);
    float sc[4], mp2c[4];
    int lc[4];
    #pragma unroll
    for (int ni = 0; ni < 4; ++ni) {
        int cl = wn * 64 + ni * 16 + lm;
        sc[ni]   = s_sqc[cl];
        mp2c[ni] = s_mp2c[cl];
        lc[ni]   = s_labc[cl];
    }
    float vminc[4];
    #pragma unroll
    for (int ni = 0; ni < 4; ++ni) vminc[ni] = INFF;

    #pragma unroll
    for (int mi = 0; mi < 8; ++mi) {
        #pragma unroll
        for (int v = 0; v < 4; ++v) {
            int rl = wm * 128 + mi * 16 + ls * 4 + v;
            float mp2r = s_mp2r[rl];
            float sr   = s_sqr[rl];
            int   li   = s_labr[rl];
            float vminr = INFF;
            #pragma unroll
            for (int ni = 0; ni < 4; ++ni) {
                float d2 = fmaf(-2.0f, acc[mi][ni][v], sr + sc[ni]);
                bool neq = (li != lc[ni]);
                vminr     = fminf(vminr,     (neq && d2 > mp2r)     ? d2 : INFF);
                vminc[ni] = fminf(vminc[ni], (neq && d2 > mp2c[ni]) ? d2 : INFF);
            }
            #pragma unroll
            for (int off = 8; off; off >>= 1)
                vminr = fminf(vminr, __shfl_xor(vminr, off, 64));
            if (lm == 0 && __float_as_uint(vminr) != INF_BITS)
                atomicMin(&minbits[i0 + rl], __float_as_uint(vminr));
        }
    }
    #pragma unroll
    for (int ni = 0; ni < 4; ++ni) {
        float vc = vminc[ni];
        vc = fminf(vc, __shfl_xor(vc, 16, 64));
        vc = fminf(vc, __shfl_xor(vc, 32, 64));
        if (ls == 0 && __float_as_uint(vc) != INF_BITS)
            atomicMin(&minbits[j0 + wn * 64 + ni * 16 + lm], __float_as_uint(vc));
    }
}

// ---------------------------------------------------------------------------
// K4: final reduction (unchanged).
// ---------------------------------------------------------------------------
__global__ __launch_bounds__(1024) void k_finish(const float* __restrict__ meanpos,
        const float* __restrict__ pcinv, const int* __restrict__ poscnt,
        const unsigned* __restrict__ minbits, float* __restrict__ out, int Bn) {
    float lsum = 0.f; int lcnt = 0;
    for (int i = threadIdx.x; i < Bn; i += 1024) {
        int pc = poscnt[i];
        bool valid = (pc > 1) && (pc < Bn);
        unsigned mb = minbits[i];
        if (valid && mb != INF_BITS) {
            float v = fmaf(meanpos[i], pcinv[i], MARGIN - sqrtf(__uint_as_float(mb)));
            lsum += (v > 0.f) ? v : 0.f;
            lcnt += 1;
        }
    }
    __shared__ float ssum[16]; __shared__ int scnt[16];
    int lane = threadIdx.x & 63, wid = threadIdx.x >> 6;
    #pragma unroll
    for (int off = 32; off; off >>= 1) {
        lsum += __shfl_down(lsum, off, 64);
        lcnt += __shfl_down(lcnt, off, 64);
    }
    if (lane == 0) { ssum[wid] = lsum; scnt[wid] = lcnt; }
    __syncthreads();
    if (threadIdx.x == 0) {
        float s = 0.f; int c = 0;
        #pragma unroll
        for (int q = 0; q < 16; ++q) { s += ssum[q]; c += scnt[q]; }
        out[0] = (c > 0) ? s / (float)c : 0.f;
    }
}

// ---------------------------------------------------------------------------
extern "C" void kernel_launch(void* const* d_in, const int* in_sizes, int n_in,
                              void* d_out, int out_size, void* d_ws, size_t ws_size,
                              hipStream_t stream) {
    const float* x = (const float*)d_in[0];
    const int* lab = (const int*)d_in[1];
    int Bn = in_sizes[1];                 // 8192; D fixed at 512

    size_t nd = (size_t)(Bn + PADR) * D;  // padded for banded over-read (K2)
    unsigned short* fh = (unsigned short*)d_ws;
    float* sqp        = (float*)(fh + nd);
    float* meanpos    = sqp + Bn;         // raw dist-sums
    float* pcinv      = meanpos + Bn;
    int* poscnt       = (int*)(pcinv + Bn);
    unsigned* minbits = (unsigned*)(poscnt + Bn);
    int* pos          = (int*)(minbits + Bn);
    int* labp         = pos + Bn;
    int* cstart_g     = labp + Bn;
    int* ccnt_g       = cstart_g + NCLS;

    k_bucket<<<1, 1024, 0, stream>>>(lab, Bn, pos, labp, cstart_g, ccnt_g,
                                     meanpos, pcinv, poscnt, minbits);
    k_normalize<<<Bn / 4, 256, 0, stream>>>(x, pos, fh, sqp);
    k_posband3<<<Bn / 16, 256, 0, stream>>>(fh, sqp, labp, cstart_g, ccnt_g,
                                            meanpos, Bn);
    int nbr = Bn / 256;                   // 32 row-tiles
    int T = nbr * nbr + nbr;              // sum_I (2I+2) = 1056
    k_minsh_mfma<<<T, 256, 0, stream>>>(fh, sqp, labp, meanpos, pcinv, minbits);
    k_finish<<<1, 1024, 0, stream>>>(meanpos, pcinv, poscnt, minbits,
                                     (float*)d_out, Bn);
}

// Round 6
// 159.135 us; speedup vs baseline: 1.1521x; 1.1174x over previous
//
#include <hip/hip_runtime.h>
#include <math.h>

#define EPS_N 1e-12f
#define MARGIN 0.3f
#define INF_BITS 0x7f800000u
#define NCLS 128     // label space (randint(0,128))
#define D 512
#define PADR 256     // padded rows after fh (kept for safety margins)

typedef __attribute__((ext_vector_type(8))) short short8;   // 8 bf16 = 4 VGPRs
typedef __attribute__((ext_vector_type(4))) float float4v;  // MFMA 16x16 accum

__device__ __forceinline__ unsigned short f2bf(float f) {   // RNE bf16
    unsigned u = __float_as_uint(f);
    u += 0x7fff + ((u >> 16) & 1);
    return (unsigned short)(u >> 16);
}
__device__ __forceinline__ void gl16(const void* g, void* l) {
    // 16B async global->LDS; global addr per-lane, LDS dest = uniform base + lane*16
    __builtin_amdgcn_global_load_lds((const __attribute__((address_space(1))) void*)g,
                                     (__attribute__((address_space(3))) void*)l, 16, 0, 0);
}

// ---------------------------------------------------------------------------
// K0: one-block bucketing, coalesced-metadata (unchanged).
// ---------------------------------------------------------------------------
__global__ __launch_bounds__(1024) void k_bucket(const int* __restrict__ lab, int Bn,
        int* __restrict__ pos, int* __restrict__ labp,
        int* __restrict__ cstart_g, int* __restrict__ ccnt_g,
        float* __restrict__ meanpos, float* __restrict__ pcinv,
        int* __restrict__ poscnt, unsigned* __restrict__ minbits) {
    __shared__ int cnt[NCLS], cs[NCLS + 1], off[NCLS], sa[NCLS], sb[NCLS];
    int tid = threadIdx.x;
    if (tid < NCLS) cnt[tid] = 0;
    __syncthreads();
    for (int i = tid; i < Bn; i += 1024) atomicAdd(&cnt[lab[i] & (NCLS - 1)], 1);
    __syncthreads();
    if (tid < NCLS) sa[tid] = cnt[tid];
    __syncthreads();
    int* src = sa; int* dst = sb;
    for (int ofs = 1; ofs < NCLS; ofs <<= 1) {          // Hillis-Steele inclusive
        if (tid < NCLS) dst[tid] = src[tid] + ((tid >= ofs) ? src[tid - ofs] : 0);
        __syncthreads();
        int* t = src; src = dst; dst = t;
    }
    if (tid < NCLS) {
        int ex = src[tid] - cnt[tid];                   // exclusive
        cs[tid] = ex;
        off[tid] = ex;
        cstart_g[tid] = ex;
        ccnt_g[tid] = cnt[tid];
    }
    if (tid == 0) cs[NCLS] = Bn;
    __syncthreads();
    // coalesced per-slot metadata: class(p) = largest l with cs[l] <= p
    for (int p = tid; p < Bn; p += 1024) {
        int lo = 0, hi = NCLS - 1;
        #pragma unroll
        for (int s = 0; s < 7; ++s) {
            int mid = (lo + hi + 1) >> 1;
            if (cs[mid] <= p) lo = mid; else hi = mid - 1;
        }
        int l = lo, m = cnt[l];
        labp[p] = l;
        poscnt[p] = m;
        pcinv[p] = 1.0f / (float)m;
        meanpos[p] = 0.f;
        minbits[p] = INF_BITS;
    }
    // pos scatter (reads coalesced; only pos[] store is scattered-by-class)
    for (int i = tid; i < Bn; i += 1024) {
        int l = lab[i] & (NCLS - 1);
        pos[i] = atomicAdd(&off[l], 1);
    }
}

// ---------------------------------------------------------------------------
// K1: normalize; one wave per row, no __syncthreads (unchanged).
// ---------------------------------------------------------------------------
__global__ __launch_bounds__(256) void k_normalize(const float* __restrict__ x,
        const int* __restrict__ pos, unsigned short* __restrict__ fh,
        float* __restrict__ sqp) {
    int w = threadIdx.x >> 6, L = threadIdx.x & 63;
    int row = blockIdx.x * 4 + w;
    const float* xr = x + (size_t)row * D + L * 8;
    float4 a = *(const float4*)xr;
    float4 b = *(const float4*)(xr + 4);
    float ss = a.x * a.x;
    ss = fmaf(a.y, a.y, ss); ss = fmaf(a.z, a.z, ss); ss = fmaf(a.w, a.w, ss);
    ss = fmaf(b.x, b.x, ss); ss = fmaf(b.y, b.y, ss);
    ss = fmaf(b.z, b.z, ss); ss = fmaf(b.w, b.w, ss);
    #pragma unroll
    for (int off = 32; off; off >>= 1) ss += __shfl_xor(ss, off, 64);
    float inv = 1.0f / fmaxf(sqrtf(ss), EPS_N);
    int prow = pos[row];
    if (L == 0) sqp[prow] = ss * inv * inv;
    ushort4 h0, h1;
    h0.x = f2bf(a.x * inv); h0.y = f2bf(a.y * inv);
    h0.z = f2bf(a.z * inv); h0.w = f2bf(a.w * inv);
    h1.x = f2bf(b.x * inv); h1.y = f2bf(b.y * inv);
    h1.z = f2bf(b.z * inv); h1.w = f2bf(b.w * inv);
    unsigned short* dst = fh + (size_t)prow * D + L * 8;
    *(ushort4*)dst = h0;
    *(ushort4*)(dst + 4) = h1;
}

// ---------------------------------------------------------------------------
// K2 (R17 rewrite): per-CLASS positive stats. One block per class: stage the
// class's rows ONCE per K-chunk (vs banded version's ~4x redundant staging
// across row-blocks -> 74 MB; now ~8.4 MB), MFMA the full n x n dot block,
// masked sqrt row-sums, PLAIN store to meanpos (single writer, no atomics).
// Handles n>128 generically via row/col chunking; common case n~64 runs the
// symmetric fast path (A aliases B, SB staging skipped).
// ---------------------------------------------------------------------------
__global__ __launch_bounds__(256) void k_posclass(
    const unsigned short* __restrict__ fh, const float* __restrict__ sqp,
    const int* __restrict__ cstart_g, const int* __restrict__ ccnt_g,
    float* __restrict__ meanpos)
{
    const int c = blockIdx.x;
    const int s = cstart_g[c], n = ccnt_g[c];
    if (n <= 1) return;                         // no positives; meanpos stays 0

    __shared__ unsigned short SA[128 * 128];    // row chunk   [r][K128] 32 KB
    __shared__ unsigned short SB[128 * 128];    // col chunk   [r][K128] 32 KB
    __shared__ float sqr_sh[128], sqs[128], rs[128];

    const int tid = threadIdx.x, w = tid >> 6, L = tid & 63;
    const int lm = L & 15, ls = L >> 4;

    for (int rb = 0; rb < n; rb += 128) {
        const int nr = min(128, n - rb);
        __syncthreads();
        if (tid < 128) {
            rs[tid] = 0.f;
            sqr_sh[tid] = (tid < nr) ? sqp[s + rb + tid] : 0.f;
        }
        for (int cb = 0; cb < n; cb += 128) {
            const int m = min(128, n - cb);
            const bool same = (rb == cb);
            __syncthreads();                    // prior epilogue done; sqs free
            if (tid < 128) sqs[tid] = (tid < m) ? sqp[s + cb + tid] : 0.f;

            float4v acc[8][2];
            #pragma unroll
            for (int rt = 0; rt < 8; ++rt)
                #pragma unroll
                for (int ct = 0; ct < 2; ++ct) acc[rt][ct] = (float4v){0.f, 0.f, 0.f, 0.f};

            for (int k0 = 0; k0 < D; k0 += 128) {
                __syncthreads();                // prev MFMA reads done; bufs free
                // stage SA rows [rb, rb+nr): 2048 slots, 8 gl16/thread
                #pragma unroll
                for (int q = 0; q < 8; ++q) {
                    int slot = tid + 256 * q;   // (row r = slot>>4, seg e = slot&15)
                    int r = slot >> 4;
                    int u = (slot & 15) ^ (r & 15);   // pre-swizzled global seg
                    if (r < nr)
                        gl16(fh + (size_t)(s + rb + r) * D + k0 + u * 8,
                             &SA[(w * 64 + 256 * q) * 8]);
                }
                if (!same) {
                    #pragma unroll
                    for (int q = 0; q < 8; ++q) {
                        int slot = tid + 256 * q;
                        int r = slot >> 4;
                        int u = (slot & 15) ^ (r & 15);
                        if (r < m)
                            gl16(fh + (size_t)(s + cb + r) * D + k0 + u * 8,
                                 &SB[(w * 64 + 256 * q) * 8]);
                    }
                }
                __syncthreads();                // drains vmcnt: chunk landed
                const unsigned short* Bb = same ? SA : SB;
                #pragma unroll
                for (int h = 0; h < 4; ++h) {   // K=128 in 4 MFMA sub-steps
                    short8 bf[2];
                    #pragma unroll
                    for (int ct = 0; ct < 2; ++ct) {
                        int cr = w * 32 + ct * 16 + lm;
                        bf[ct] = *(const short8*)&Bb[cr * 128 + (((h * 4 + ls) ^ (cr & 15))) * 8];
                    }
                    #pragma unroll
                    for (int rt = 0; rt < 8; ++rt) {
                        int ar = rt * 16 + lm;
                        short8 af = *(const short8*)&SA[ar * 128 + (((h * 4 + ls) ^ (ar & 15))) * 8];
                        #pragma unroll
                        for (int ct = 0; ct < 2; ++ct)
                            acc[rt][ct] = __builtin_amdgcn_mfma_f32_16x16x32_bf16(af, bf[ct], acc[rt][ct], 0, 0, 0);
                    }
                }
            }
            // epilogue: masked dist row-sums. C/D: row = rt*16+ls*4+v, col = w*32+ct*16+lm
            #pragma unroll
            for (int rt = 0; rt < 8; ++rt) {
                #pragma unroll
                for (int v = 0; v < 4; ++v) {
                    int ri = rt * 16 + ls * 4 + v;
                    float sr = sqr_sh[ri];
                    float sum = 0.f;
                    #pragma unroll
                    for (int ct = 0; ct < 2; ++ct) {
                        int ci = w * 32 + ct * 16 + lm;
                        float d2 = sr + sqs[ci] - 2.0f * acc[rt][ct][v];
                        bool ok = (ri < nr) && (ci < m) && (rb + ri != cb + ci) && (d2 > 0.f);
                        sum += ok ? sqrtf(d2) : 0.f;
                    }
                    #pragma unroll
                    for (int off = 8; off; off >>= 1) sum += __shfl_xor(sum, off, 64);
                    if (lm == 0 && sum != 0.f) atomicAdd(&rs[ri], sum);
                }
            }
        }
        __syncthreads();
        if (tid < nr) meanpos[s + rb + tid] = rs[tid];   // single writer: plain store
    }
}

// ---------------------------------------------------------------------------
// K3: hi-only bf16 MFMA GEMM + fused semi-hard min — VERBATIM R8 form (the
// measured best: 72.6 us at ~97% of its LDS-BW structural ceiling; every
// pipelined/bigger-tile variant R12-R16 lost more in achieved-fraction than
// it gained in ceiling). 128x128 triangular tiles, 4 blocks/CU antiphase.
// ---------------------------------------------------------------------------
#define BKG 64

__global__ __launch_bounds__(256, 4) void k_minsh_mfma(
    const unsigned short* __restrict__ fh, const float* __restrict__ sqp,
    const int* __restrict__ labp, const float* __restrict__ meanpos,
    const float* __restrict__ pcinv, unsigned* __restrict__ minbits)
{
    int t = blockIdx.x;
    int rq = (int)((sqrtf(8.0f * (float)t + 1.0f) - 1.0f) * 0.5f);
    while ((rq + 1) * (rq + 2) / 2 <= t) ++rq;
    while (rq * (rq + 1) / 2 > t) --rq;
    int cq = t - rq * (rq + 1) / 2;
    const int i0 = cq * 128, j0 = rq * 128;
    const bool diag = (i0 == j0);

    __shared__ unsigned short LA[2][128 * BKG];   // 32 KB
    __shared__ float s_mp2r[128], s_mp2c[128], s_sqr[128], s_sqc[128];
    __shared__ int s_labr[128], s_labc[128];

    const int tid = threadIdx.x;
    const int w = tid >> 6, L = tid & 63;

    if (tid < 128) {
        float mp = meanpos[i0 + tid] * pcinv[i0 + tid];
        s_mp2r[tid] = mp * mp;
        s_sqr[tid]  = sqp[i0 + tid];
        s_labr[tid] = labp[i0 + tid];
    } else {
        int q = tid - 128;
        float mp = meanpos[j0 + q] * pcinv[j0 + q];
        s_mp2c[q] = mp * mp;
        s_sqc[q]  = sqp[j0 + q];
        s_labc[q] = labp[j0 + q];
    }

    const unsigned short* msrc = fh + (size_t)((w < 2) ? i0 : j0) * D;
    unsigned short* mylds = &LA[(w < 2) ? 0 : 1][(w & 1) * 64 * BKG];
    const int srow = L >> 3;
    const int sseg = L & 7;

    float4v acc[4][4];
    #pragma unroll
    for (int a = 0; a < 4; ++a)
        #pragma unroll
        for (int bq = 0; bq < 4; ++bq) acc[a][bq] = (float4v){0.f, 0.f, 0.f, 0.f};

    const int rw = (w >> 1) * 64, cw = (w & 1) * 64;
    const int lm = L & 15, ls = L >> 4;

    for (int k0 = 0; k0 < D; k0 += BKG) {
        __syncthreads();
        #pragma unroll
        for (int it = 0; it < 8; ++it) {
            int rmat = (w & 1) * 64 + it * 8 + srow;
            int seg = sseg ^ (rmat & 7);
            gl16(msrc + (size_t)rmat * D + k0 + seg * 8, mylds + it * 512);
        }
        __syncthreads();
        #pragma unroll
        for (int h = 0; h < 2; ++h) {
            short8 ah[4], bh[4];
            #pragma unroll
            for (int mi = 0; mi < 4; ++mi) {
                int r = rw + mi * 16 + lm;
                int slot = r * 8 + ((h * 4 + ls) ^ (r & 7));
                ah[mi] = *(const short8*)&LA[0][slot * 8];
            }
            #pragma unroll
            for (int ni = 0; ni < 4; ++ni) {
                int cc = cw + ni * 16 + lm;
                int slot = cc * 8 + ((h * 4 + ls) ^ (cc & 7));
                bh[ni] = *(const short8*)&LA[1][slot * 8];
            }
            #pragma unroll
            for (int ni = 0; ni < 4; ++ni)
                #pragma unroll
                for (int mi = 0; mi < 4; ++mi)
                    acc[mi][ni] = __builtin_amdgcn_mfma_f32_16x16x32_bf16(ah[mi], bh[ni], acc[mi][ni], 0, 0, 0);
        }
    }

    // d2-space epilogue. C/D: row = rw+mi*16+ls*4+v, col = cw+ni*16+lm
    const float INFF = __uint_as_float(INF_BITS);
    float sc[4], mp2c[4];
    int lc[4];
    #pragma unroll
    for (int ni = 0; ni < 4; ++ni) {
        int cl = cw + ni * 16 + lm;
        sc[ni]   = s_sqc[cl];
        mp2c[ni] = s_mp2c[cl];
        lc[ni]   = s_labc[cl];
    }
    float vminc[4];
    #pragma unroll
    for (int ni = 0; ni < 4; ++ni) vminc[ni] = INFF;

    #pragma unroll
    for (int mi = 0; mi < 4; ++mi) {
        #pragma unroll
        for (int v = 0; v < 4; ++v) {
            int rl = rw + mi * 16 + ls * 4 + v;
            float mp2r = s_mp2r[rl];
            float sr   = s_sqr[rl];
            int   li   = s_labr[rl];
            float vminr = INFF;
            #pragma unroll
            for (int ni = 0; ni < 4; ++ni) {
                float d2 = fmaf(-2.0f, acc[mi][ni][v], sr + sc[ni]);
                bool neq = (li != lc[ni]);
                vminr     = fminf(vminr,     (neq && d2 > mp2r)     ? d2 : INFF);
                vminc[ni] = fminf(vminc[ni], (neq && d2 > mp2c[ni]) ? d2 : INFF);
            }
            #pragma unroll
            for (int off = 8; off; off >>= 1)
                vminr = fminf(vminr, __shfl_xor(vminr, off, 64));
            if (lm == 0 && __float_as_uint(vminr) != INF_BITS)
                atomicMin(&minbits[i0 + rl], __float_as_uint(vminr));
        }
    }
    if (!diag) {
        #pragma unroll
        for (int ni = 0; ni < 4; ++ni) {
            float vc = vminc[ni];
            vc = fminf(vc, __shfl_xor(vc, 16, 64));
            vc = fminf(vc, __shfl_xor(vc, 32, 64));
            if (ls == 0 && __float_as_uint(vc) != INF_BITS)
                atomicMin(&minbits[j0 + cw + ni * 16 + lm], __float_as_uint(vc));
        }
    }
}

// ---------------------------------------------------------------------------
// K4: final reduction (unchanged).
// ---------------------------------------------------------------------------
__global__ __launch_bounds__(1024) void k_finish(const float* __restrict__ meanpos,
        const float* __restrict__ pcinv, const int* __restrict__ poscnt,
        const unsigned* __restrict__ minbits, float* __restrict__ out, int Bn) {
    float lsum = 0.f; int lcnt = 0;
    for (int i = threadIdx.x; i < Bn; i += 1024) {
        int pc = poscnt[i];
        bool valid = (pc > 1) && (pc < Bn);
        unsigned mb = minbits[i];
        if (valid && mb != INF_BITS) {
            float v = fmaf(meanpos[i], pcinv[i], MARGIN - sqrtf(__uint_as_float(mb)));
            lsum += (v > 0.f) ? v : 0.f;
            lcnt += 1;
        }
    }
    __shared__ float ssum[16]; __shared__ int scnt[16];
    int lane = threadIdx.x & 63, wid = threadIdx.x >> 6;
    #pragma unroll
    for (int off = 32; off; off >>= 1) {
        lsum += __shfl_down(lsum, off, 64);
        lcnt += __shfl_down(lcnt, off, 64);
    }
    if (lane == 0) { ssum[wid] = lsum; scnt[wid] = lcnt; }
    __syncthreads();
    if (threadIdx.x == 0) {
        float s = 0.f; int c = 0;
        #pragma unroll
        for (int q = 0; q < 16; ++q) { s += ssum[q]; c += scnt[q]; }
        out[0] = (c > 0) ? s / (float)c : 0.f;
    }
}

// ---------------------------------------------------------------------------
extern "C" void kernel_launch(void* const* d_in, const int* in_sizes, int n_in,
                              void* d_out, int out_size, void* d_ws, size_t ws_size,
                              hipStream_t stream) {
    const float* x = (const float*)d_in[0];
    const int* lab = (const int*)d_in[1];
    int Bn = in_sizes[1];                 // 8192; D fixed at 512

    size_t nd = (size_t)(Bn + PADR) * D;
    unsigned short* fh = (unsigned short*)d_ws;
    float* sqp        = (float*)(fh + nd);
    float* meanpos    = sqp + Bn;         // raw dist-sums
    float* pcinv      = meanpos + Bn;
    int* poscnt       = (int*)(pcinv + Bn);
    unsigned* minbits = (unsigned*)(poscnt + Bn);
    int* pos          = (int*)(minbits + Bn);
    int* labp         = pos + Bn;
    int* cstart_g     = labp + Bn;
    int* ccnt_g       = cstart_g + NCLS;

    k_bucket<<<1, 1024, 0, stream>>>(lab, Bn, pos, labp, cstart_g, ccnt_g,
                                     meanpos, pcinv, poscnt, minbits);
    k_normalize<<<Bn / 4, 256, 0, stream>>>(x, pos, fh, sqp);
    k_posclass<<<NCLS, 256, 0, stream>>>(fh, sqp, cstart_g, ccnt_g, meanpos);
    int nb = Bn / 128;
    int T = nb * (nb + 1) / 2;            // 2080
    k_minsh_mfma<<<T, 256, 0, stream>>>(fh, sqp, labp, meanpos, pcinv, minbits);
    k_finish<<<1, 1024, 0, stream>>>(meanpos, pcinv, poscnt, minbits,
                                     (float*)d_out, Bn);
}